// Round 4
// baseline (608.303 us; speedup 1.0000x reference)
//
#include <hip/hip_runtime.h>
#include <stdint.h>

typedef float  f32x4  __attribute__((ext_vector_type(4)));
typedef __bf16 bf16x8 __attribute__((ext_vector_type(8)));
typedef unsigned int   u32;
typedef unsigned short u16;
typedef unsigned long long u64;
typedef u32 u32x4 __attribute__((ext_vector_type(4)));

#define M_TOT 8192
#define N_TOT 4096
#define K_DIN 4096
#define RANK  32
#define KPAD  128          // t-path zero-padded to 2 K-tiles
#define NTILE 130          // (2*4096 + 128) / 64

__device__ __forceinline__ u16 f2bf(float f) {
  union { float f; u32 u; } v; v.f = f;
  u32 r = v.u + 0x7fffu + ((v.u >> 16) & 1u);
  return (u16)(r >> 16);
}

// ---- P0: a_sb[r][k] = bf16(lora_a[r][k] * smooth[k])  (32x4096)
__global__ void prep_as_k(const float* __restrict__ la, const float* __restrict__ ss,
                          u16* __restrict__ asb) {
  int i = blockIdx.x * 256 + threadIdx.x;
  f32x4 v = ((const f32x4*)la)[i];
  f32x4 s = ((const f32x4*)ss)[i & 1023];
  f32x4 p = v * s;
  alignas(8) u16 o[4] = { f2bf(p[0]), f2bf(p[1]), f2bf(p[2]), f2bf(p[3]) };
  *(u64*)(asb + 4 * (size_t)i) = *(const u64*)o;
}

// ---- generic fp32 -> bf16 cast (4/thread)
__global__ void cvt_bf16_k(const float* __restrict__ in, u16* __restrict__ out, int n4) {
  int i = blockIdx.x * 256 + threadIdx.x;
  if (i >= n4) return;
  f32x4 v = ((const f32x4*)in)[i];
  alignas(8) u16 o[4] = { f2bf(v[0]), f2bf(v[1]), f2bf(v[2]), f2bf(v[3]) };
  *(u64*)(out + 4 * (size_t)i) = *(const u64*)o;
}

// ---- lora_b [4096][32] fp32 -> bf16 into [4096][KPAD] (cols 0-31; pad pre-zeroed)
__global__ void cvt_lb_k(const float* __restrict__ in, u16* __restrict__ out) {
  int i = blockIdx.x * 256 + threadIdx.x;      // 32768 float4s
  f32x4 v = ((const f32x4*)in)[i];
  int row = i >> 3, c = (i & 7) * 4;
  alignas(8) u16 o[4] = { f2bf(v[0]), f2bf(v[1]), f2bf(v[2]), f2bf(v[3]) };
  *(u64*)(out + (size_t)row * KPAD + c) = *(const u64*)o;
}

// ---- P1: smooth + blockwise fake-quant -> xq (bf16); raw x -> xb (bf16)
__global__ void prep_x_k(const float* __restrict__ x, const float* __restrict__ ss,
                         u16* __restrict__ xq, u16* __restrict__ xb) {
  int m = blockIdx.x;
  int t = threadIdx.x;
  size_t off = (size_t)m * K_DIN + t * 16;
  const f32x4* xp = (const f32x4*)(x + off);
  const f32x4* sp = (const f32x4*)(ss + t * 16);
  float xs[16];
  alignas(16) u16 rb[16], qb[16];
  float amax = 0.0f;
  #pragma unroll
  for (int i = 0; i < 4; ++i) {
    f32x4 a = xp[i], s = sp[i];
    #pragma unroll
    for (int j = 0; j < 4; ++j) {
      float xr = a[j];
      float v  = xr * s[j];
      xs[i*4+j] = v;
      amax = fmaxf(amax, fabsf(v));
      rb[i*4+j] = f2bf(xr);
    }
  }
  amax = fmaxf(amax, 1e-12f);
  float scale = amax / 7.0f;
  #pragma unroll
  for (int i = 0; i < 16; ++i) {
    float r = rintf(xs[i] / scale);
    r = fminf(7.0f, fmaxf(-7.0f, r));
    qb[i] = f2bf(r * scale);
  }
  ((u32x4*)(xq + off))[0] = ((const u32x4*)qb)[0];
  ((u32x4*)(xq + off))[1] = ((const u32x4*)qb)[1];
  ((u32x4*)(xb + off))[0] = ((const u32x4*)rb)[0];
  ((u32x4*)(xb + off))[1] = ((const u32x4*)rb)[1];
}

// ---- P2: t[m][r] = sum_k xb[m][k] * a_sb[r][k] via MFMA, into [M][KPAD] (pad pre-zeroed)
__global__ __launch_bounds__(256)
void lora_t_mfma_k(const u16* __restrict__ xb, const u16* __restrict__ asb,
                   u16* __restrict__ tb) {
  const int wave = threadIdx.x >> 6;
  const int lane = threadIdx.x & 63;
  const int lr = lane & 15, lg = lane >> 4;
  const int m0 = blockIdx.x * 64 + wave * 16;
  f32x4 acc0 = {}, acc1 = {};
  for (int k0 = 0; k0 < K_DIN; k0 += 32) {
    bf16x8 a  = *(const bf16x8*)(xb  + (size_t)(m0 + lr) * K_DIN + k0 + lg * 8);
    bf16x8 b0 = *(const bf16x8*)(asb + (size_t)lr        * K_DIN + k0 + lg * 8);
    bf16x8 b1 = *(const bf16x8*)(asb + (size_t)(16 + lr) * K_DIN + k0 + lg * 8);
    acc0 = __builtin_amdgcn_mfma_f32_16x16x32_bf16(a, b0, acc0, 0, 0, 0);
    acc1 = __builtin_amdgcn_mfma_f32_16x16x32_bf16(a, b1, acc1, 0, 0, 0);
  }
  #pragma unroll
  for (int j = 0; j < 4; ++j) {
    const int row = m0 + lg * 4 + j;
    tb[(size_t)row * KPAD + lr]      = f2bf(acc0[j]);
    tb[(size_t)row * KPAD + 16 + lr] = f2bf(acc1[j]);
  }
}

// ================= main GEMM: 256x256 tile, BK=64, 8-phase (T1-T5) =================
__device__ __forceinline__ void gld_lds16(const u16* g, u16* l) {
  __builtin_amdgcn_global_load_lds((const __attribute__((address_space(1))) u32*)g,
                                   (__attribute__((address_space(3))) u32*)l,
                                   16, 0, 0);
}

// barrier: sched_barrier pins ordering (no hoisting of gld/ds_read across),
// builtin s_barrier is modeled precisely -> NO vmcnt drain (unlike asm/syncthreads)
#define BARX() do { __builtin_amdgcn_sched_barrier(0);                               \
                    __builtin_amdgcn_s_barrier();                                    \
                    __builtin_amdgcn_sched_barrier(0); } while (0)
#define VMW6() asm volatile("s_waitcnt vmcnt(6)" ::: "memory")

#define BUF1 32768

// ds-load A-subtile (4 m-frags x 2 ks) / B-subtile (2 n-frags x 2 ks)
#define LDA(bufel, mh) do { _Pragma("unroll")                                        \
  for (int m_ = 0; m_ < 4; ++m_) {                                                   \
    Ar[m_][0] = *(const bf16x8*)(smem + (bufel) + aoff + ((mh)*4+m_)*1024 + blk0);    \
    Ar[m_][1] = *(const bf16x8*)(smem + (bufel) + aoff + ((mh)*4+m_)*1024 + blk1);    \
  } } while (0)

#define LDB(bufel, nh) do { _Pragma("unroll")                                        \
  for (int n_ = 0; n_ < 2; ++n_) {                                                   \
    Br[(nh)*2+n_][0] = *(const bf16x8*)(smem + (bufel) + boff + ((nh)*2+n_)*1024 + blk0); \
    Br[(nh)*2+n_][1] = *(const bf16x8*)(smem + (bufel) + boff + ((nh)*2+n_)*1024 + blk1); \
  } } while (0)

// one C-quadrant: 4m x 2n x 2ks = 16 MFMA, setprio-wrapped (T5)
#define MMQ(mh, nh) do {                                                             \
  __builtin_amdgcn_s_setprio(1);                                                     \
  _Pragma("unroll")                                                                  \
  for (int m_ = 0; m_ < 4; ++m_) { _Pragma("unroll")                                 \
    for (int n_ = 0; n_ < 2; ++n_) {                                                 \
      acc[(mh)*4+m_][(nh)*2+n_] = __builtin_amdgcn_mfma_f32_16x16x32_bf16(           \
          Ar[m_][0], Br[(nh)*2+n_][0], acc[(mh)*4+m_][(nh)*2+n_], 0, 0, 0);          \
      acc[(mh)*4+m_][(nh)*2+n_] = __builtin_amdgcn_mfma_f32_16x16x32_bf16(           \
          Ar[m_][1], Br[(nh)*2+n_][1], acc[(mh)*4+m_][(nh)*2+n_], 0, 0, 0);          \
    } }                                                                              \
  __builtin_amdgcn_s_setprio(0);                                                     \
} while (0)

__global__ __launch_bounds__(512, 2)
void gemm8_k(const u16* __restrict__ xq, const u16* __restrict__ xb,
             const u16* __restrict__ tb, const u16* __restrict__ wqb,
             const u16* __restrict__ wsb, const u16* __restrict__ lbp,
             const float* __restrict__ bias, float* __restrict__ out) {
  extern __shared__ u16 smem[];           // 2 bufs x (A 16384 + B 16384) elems = 128 KiB
  const int tid  = threadIdx.x;
  const int wave = tid >> 6;
  const int lane = tid & 63;
  const int lr = lane & 15, lg = lane >> 4;
  const int wm = wave >> 2, wn = wave & 3;

  // T1: bijective XCD swizzle (512 % 8 == 0)
  const int wg  = blockIdx.x;
  const int swz = (wg & 7) * 64 + (wg >> 3);
  const int m0 = (swz >> 4) * 256;
  const int n0 = (swz & 15) * 256;

  // ds_read addressing (T2 swizzle: 16B-block cb ^= row&7; row&7 == lr&7)
  const int aoff = wm * 8192 + lr * 64;
  const int boff = 16384 + wn * 4096 + lr * 64;
  const int e7   = lr & 7;
  const int blk0 = ((0 + lg) ^ e7) * 8;
  const int blk1 = ((4 + lg) ^ e7) * 8;

  // staging: thread t covers row tid>>3 (of 64-row issue), source col pre-swizzled
  const int srow = tid >> 3;
  const int scol = ((tid & 7) ^ (srow & 7)) * 8;
  const int woff = wave * 512;

  bf16x8 Ar[4][2], Br[4][2];
  f32x4 acc[8][4] = {};

  // stage one half-tile (128 rows x 64 k) = 2 x global_load_lds per wave
  auto stage = [&](int tt, int mat, int h, int bufel) {
    if (tt > NTILE - 1) tt = NTILE - 1;          // junk-clamp (dead data, never read)
    const u16* p; size_t stride; int kof;
    if (tt < 64)       { p = mat ? wqb : xq; stride = 4096; kof = tt * 64; }
    else if (tt < 128) { p = mat ? wsb : xb; stride = 4096; kof = (tt - 64) * 64; }
    else               { p = mat ? lbp : tb; stride = KPAD; kof = (tt - 128) * 64; }
    const int rb = (mat ? n0 : m0) + h * 128 + srow;
    u16* dst = smem + bufel + mat * 16384 + h * 8192 + woff;
    gld_lds16(p + (size_t)rb * stride + kof + scol, dst);
    gld_lds16(p + (size_t)(rb + 64) * stride + kof + scol, dst + 4096);
  };

  // prologue: tile0 full (buf0), then t1.B0,B1,A0 (buf1); gate tile0 (oldest 8 of 14)
  stage(0, 0, 0, 0);     stage(0, 0, 1, 0);
  stage(0, 1, 0, 0);     stage(0, 1, 1, 0);
  stage(1, 1, 0, BUF1);  stage(1, 1, 1, BUF1);
  stage(1, 0, 0, BUF1);
  VMW6();
  BARX();

  for (int it = 0; it < NTILE / 2; ++it) {
    const int a = 2 * it;
    // P1: Q00(a) | stage b.A1 -> buf1 (buf1.A free since prev P7)
    LDA(0, 0); LDB(0, 0);
    stage(a + 1, 0, 1, BUF1);
    BARX(); MMQ(0, 0); BARX();
    // P2: Q01(a)
    LDB(0, 1);
    BARX(); MMQ(0, 1); BARX();
    // P3: Q11(a) | stage (a+2).B0,B1 -> buf0 (buf0.B read-done after P2)
    LDA(0, 1);
    stage(a + 2, 1, 0, 0);
    stage(a + 2, 1, 1, 0);
    BARX(); MMQ(1, 1); BARX();
    // P4: Q10(a) | stage (a+2).A0 -> buf0 (buf0.A read-done after P3); gate b complete
    stage(a + 2, 0, 0, 0);
    BARX(); MMQ(1, 0);
    VMW6();                 // oldest 8 = tile b (B0,B1,A0,A1) landed; 6 in flight
    BARX();
    // P5: Q00(b) | stage (a+2).A1 -> buf0
    LDA(BUF1, 0); LDB(BUF1, 0);
    stage(a + 2, 0, 1, 0);
    BARX(); MMQ(0, 0); BARX();
    // P6: Q01(b)
    LDB(BUF1, 1);
    BARX(); MMQ(0, 1); BARX();
    // P7: Q11(b) | stage (a+3).B0,B1 -> buf1 (buf1.B read-done after P6)
    LDA(BUF1, 1);
    stage(a + 3, 1, 0, BUF1);
    stage(a + 3, 1, 1, BUF1);
    BARX(); MMQ(1, 1); BARX();
    // P8: Q10(b) | stage (a+3).A0 -> buf1 (buf1.A read-done after P7); gate a+2 complete
    stage(a + 3, 0, 0, BUF1);
    BARX(); MMQ(1, 0);
    VMW6();                 // oldest 8 = tile a+2 landed; 6 in flight
    BARX();
  }

  // epilogue: bias + store (C/D mapping: row=...+lg*4+j, col=...+lr)
  float bv[4];
  #pragma unroll
  for (int n = 0; n < 4; ++n) bv[n] = bias[n0 + wn * 64 + n * 16 + lr];
  #pragma unroll
  for (int m = 0; m < 8; ++m) {
    const int row = m0 + wm * 128 + m * 16 + lg * 4;
    #pragma unroll
    for (int n = 0; n < 4; ++n) {
      const int col = n0 + wn * 64 + n * 16 + lr;
      float* op = out + (size_t)row * N_TOT + col;
      op[0 * (size_t)N_TOT] = acc[m][n][0] + bv[n];
      op[1 * (size_t)N_TOT] = acc[m][n][1] + bv[n];
      op[2 * (size_t)N_TOT] = acc[m][n][2] + bv[n];
      op[3 * (size_t)N_TOT] = acc[m][n][3] + bv[n];
    }
  }
}

extern "C" void kernel_launch(void* const* d_in, const int* in_sizes, int n_in,
                              void* d_out, int out_size, void* d_ws, size_t ws_size,
                              hipStream_t stream) {
  const float* x    = (const float*)d_in[0];
  const float* ss   = (const float*)d_in[1];
  const float* wq   = (const float*)d_in[2];
  const float* la   = (const float*)d_in[3];
  const float* lb   = (const float*)d_in[4];
  const float* wsp  = (const float*)d_in[5];
  const float* bias = (const float*)d_in[6];
  float* out = (float*)d_out;

  uint8_t* w = (uint8_t*)d_ws;
  u16* xq   = (u16*)w;  w += (size_t)M_TOT * K_DIN * 2;   // 64 MiB
  u16* xb   = (u16*)w;  w += (size_t)M_TOT * K_DIN * 2;   // 64 MiB
  u16* wqb  = (u16*)w;  w += (size_t)N_TOT * K_DIN * 2;   // 32 MiB
  u16* wsb  = (u16*)w;  w += (size_t)N_TOT * K_DIN * 2;   // 32 MiB
  u16* tb   = (u16*)w;  w += (size_t)M_TOT * KPAD * 2;    // 2 MiB  (adjacent: one memset)
  u16* lbp  = (u16*)w;  w += (size_t)N_TOT * KPAD * 2;    // 1 MiB
  u16* asb  = (u16*)w;                                     // 0.25 MiB

  hipMemsetAsync(tb, 0, ((size_t)M_TOT + N_TOT) * KPAD * 2, stream);
  prep_as_k<<<128, 256, 0, stream>>>(la, ss, asb);
  cvt_bf16_k<<<16384, 256, 0, stream>>>(wq,  wqb, (N_TOT * K_DIN) / 4);
  cvt_bf16_k<<<16384, 256, 0, stream>>>(wsp, wsb, (N_TOT * K_DIN) / 4);
  cvt_lb_k<<<128, 256, 0, stream>>>(lb, lbp);
  prep_x_k<<<M_TOT, 256, 0, stream>>>(x, ss, xq, xb);
  lora_t_mfma_k<<<M_TOT / 64, 256, 0, stream>>>(xb, asb, tb);

  hipFuncSetAttribute((const void*)gemm8_k,
                      hipFuncAttributeMaxDynamicSharedMemorySize, 131072);
  gemm8_k<<<dim3((N_TOT / 256) * (M_TOT / 256)), 512, 131072, stream>>>(
      xq, xb, tb, wqb, wsb, lbp, bias, out);
}

// Round 5
// 595.663 us; speedup vs baseline: 1.0212x; 1.0212x over previous
//
#include <hip/hip_runtime.h>
#include <stdint.h>

typedef float  f32x4  __attribute__((ext_vector_type(4)));
typedef __bf16 bf16x8 __attribute__((ext_vector_type(8)));
typedef unsigned int   u32;
typedef unsigned short u16;
typedef unsigned long long u64;
typedef u32 u32x4 __attribute__((ext_vector_type(4)));

#define M_TOT 8192
#define N_TOT 4096
#define K_DIN 4096
#define RANK  32
#define KCAT  8320         // 4096 (xq|wq) + 4096 (xb|ws) + 128 (t|lb zero-padded)
#define NTILE 130          // KCAT / 64

__device__ __forceinline__ u16 f2bf(float f) {
  union { float f; u32 u; } v; v.f = f;
  u32 r = v.u + 0x7fffu + ((v.u >> 16) & 1u);
  return (u16)(r >> 16);
}

// ---- P0: a_sb[r][k] = bf16(lora_a[r][k] * smooth[k])  (32x4096)
__global__ void prep_as_k(const float* __restrict__ la, const float* __restrict__ ss,
                          u16* __restrict__ asb) {
  int i = blockIdx.x * 256 + threadIdx.x;
  f32x4 v = ((const f32x4*)la)[i];
  f32x4 s = ((const f32x4*)ss)[i & 1023];
  f32x4 p = v * s;
  alignas(8) u16 o[4] = { f2bf(p[0]), f2bf(p[1]), f2bf(p[2]), f2bf(p[3]) };
  *(u64*)(asb + 4 * (size_t)i) = *(const u64*)o;
}

// ---- weight cast into B-concat [4096][KCAT] at column offset colofs
__global__ void cvt_w_k(const float* __restrict__ in, u16* __restrict__ Bb, int colofs) {
  int i = blockIdx.x * 256 + threadIdx.x;          // 4M float4s
  f32x4 v = ((const f32x4*)in)[i];
  int r = i >> 10, c = (i & 1023) * 4;
  alignas(8) u16 o[4] = { f2bf(v[0]), f2bf(v[1]), f2bf(v[2]), f2bf(v[3]) };
  *(u64*)(Bb + (size_t)r * KCAT + colofs + c) = *(const u64*)o;
}

// ---- lora_b [4096][32] -> B-concat cols 8192..8223; zero cols 8224..8319
__global__ void cvt_lb_k(const float* __restrict__ in, u16* __restrict__ Bb) {
  int i = blockIdx.x * 256 + threadIdx.x;          // 32768 float4s
  f32x4 v = ((const f32x4*)in)[i];
  int row = i >> 3, c = (i & 7) * 4;
  alignas(8) u16 o[4] = { f2bf(v[0]), f2bf(v[1]), f2bf(v[2]), f2bf(v[3]) };
  u16* rp = Bb + (size_t)row * KCAT;
  *(u64*)(rp + 2 * K_DIN + c) = *(const u64*)o;
  u16* zp = rp + 2 * K_DIN + RANK + (i & 7) * 12;  // 8 threads x 12 cols = 96 zeros
  *(u64*)(zp + 0) = 0; *(u64*)(zp + 4) = 0; *(u64*)(zp + 8) = 0;
}

// ---- P1: smooth+quant -> A-concat cols 0..4095 (xq); raw bf16 -> cols 4096..8191 (xb)
__global__ void prep_x_k(const float* __restrict__ x, const float* __restrict__ ss,
                         u16* __restrict__ Ab) {
  int m = blockIdx.x;
  int t = threadIdx.x;
  const f32x4* xp = (const f32x4*)(x + (size_t)m * K_DIN + t * 16);
  const f32x4* sp = (const f32x4*)(ss + t * 16);
  float xs[16];
  alignas(16) u16 rb[16], qb[16];
  float amax = 0.0f;
  #pragma unroll
  for (int i = 0; i < 4; ++i) {
    f32x4 a = xp[i], s = sp[i];
    #pragma unroll
    for (int j = 0; j < 4; ++j) {
      float xr = a[j];
      float v  = xr * s[j];
      xs[i*4+j] = v;
      amax = fmaxf(amax, fabsf(v));
      rb[i*4+j] = f2bf(xr);
    }
  }
  amax = fmaxf(amax, 1e-12f);
  float scale = amax / 7.0f;                       // IEEE div, matches numpy
  #pragma unroll
  for (int i = 0; i < 16; ++i) {
    float r = rintf(xs[i] / scale);                // RNE, matches jnp.round
    r = fminf(7.0f, fmaxf(-7.0f, r));
    qb[i] = f2bf(r * scale);
  }
  u16* qo = Ab + (size_t)m * KCAT + t * 16;
  ((u32x4*)qo)[0] = ((const u32x4*)qb)[0];
  ((u32x4*)qo)[1] = ((const u32x4*)qb)[1];
  u16* ro = qo + K_DIN;
  ((u32x4*)ro)[0] = ((const u32x4*)rb)[0];
  ((u32x4*)ro)[1] = ((const u32x4*)rb)[1];
}

// ---- P2: t = xb @ a_s^T via MFMA -> A-concat cols 8192..8223; zero 8224..8319
__global__ __launch_bounds__(256)
void lora_t_mfma_k(u16* __restrict__ Ab, const u16* __restrict__ asb) {
  const int wave = threadIdx.x >> 6;
  const int lane = threadIdx.x & 63;
  const int lr = lane & 15, lg = lane >> 4;
  const int m0 = blockIdx.x * 64 + wave * 16;
  f32x4 acc0 = {}, acc1 = {};
  for (int k0 = 0; k0 < K_DIN; k0 += 32) {
    bf16x8 a  = *(const bf16x8*)(Ab + (size_t)(m0 + lr) * KCAT + K_DIN + k0 + lg * 8);
    bf16x8 b0 = *(const bf16x8*)(asb + (size_t)lr        * K_DIN + k0 + lg * 8);
    bf16x8 b1 = *(const bf16x8*)(asb + (size_t)(16 + lr) * K_DIN + k0 + lg * 8);
    acc0 = __builtin_amdgcn_mfma_f32_16x16x32_bf16(a, b0, acc0, 0, 0, 0);
    acc1 = __builtin_amdgcn_mfma_f32_16x16x32_bf16(a, b1, acc1, 0, 0, 0);
  }
  #pragma unroll
  for (int j = 0; j < 4; ++j) {
    const int row = m0 + lg * 4 + j;
    Ab[(size_t)row * KCAT + 2 * K_DIN + lr]      = f2bf(acc0[j]);
    Ab[(size_t)row * KCAT + 2 * K_DIN + 16 + lr] = f2bf(acc1[j]);
  }
  // zero pad cols 8224..8319 for this block's 64 rows (4 threads/row x 24 cols)
  const int zr = blockIdx.x * 64 + (threadIdx.x >> 2);
  u16* zp = Ab + (size_t)zr * KCAT + 2 * K_DIN + RANK + (threadIdx.x & 3) * 24;
  #pragma unroll
  for (int q = 0; q < 6; ++q) *(u64*)(zp + q * 4) = 0;
}

// ================= main GEMM: 256x256 tile, BK=64, 8-phase (T1-T5) =================
__device__ __forceinline__ void gld_lds16(const u16* g, u16* l) {
  __builtin_amdgcn_global_load_lds((const __attribute__((address_space(1))) u32*)g,
                                   (__attribute__((address_space(3))) u32*)l,
                                   16, 0, 0);
}

#define BAR()  __builtin_amdgcn_s_barrier()
#define VMW6() asm volatile("s_waitcnt vmcnt(6)" ::: "memory")
#define BUF1 32768

// ds-load A-subtile (4 m-frags x 2 ks) / B-subtile (2 n-frags x 2 ks)
#define LDA(bufel, mh) do { _Pragma("unroll")                                        \
  for (int m_ = 0; m_ < 4; ++m_) {                                                   \
    Ar[m_][0] = *(const bf16x8*)(smem + (bufel) + aoff + ((mh)*4+m_)*1024 + blk0);    \
    Ar[m_][1] = *(const bf16x8*)(smem + (bufel) + aoff + ((mh)*4+m_)*1024 + blk1);    \
  } } while (0)

#define LDB(bufel, nh) do { _Pragma("unroll")                                        \
  for (int n_ = 0; n_ < 2; ++n_) {                                                   \
    Br[(nh)*2+n_][0] = *(const bf16x8*)(smem + (bufel) + boff + ((nh)*2+n_)*1024 + blk0); \
    Br[(nh)*2+n_][1] = *(const bf16x8*)(smem + (bufel) + boff + ((nh)*2+n_)*1024 + blk1); \
  } } while (0)

// one C-quadrant: 4m x 2n x 2ks = 16 MFMA, setprio-wrapped (T5)
#define MMQ(mh, nh) do {                                                             \
  __builtin_amdgcn_s_setprio(1);                                                     \
  _Pragma("unroll")                                                                  \
  for (int m_ = 0; m_ < 4; ++m_) { _Pragma("unroll")                                 \
    for (int n_ = 0; n_ < 2; ++n_) {                                                 \
      acc[(mh)*4+m_][(nh)*2+n_] = __builtin_amdgcn_mfma_f32_16x16x32_bf16(           \
          Ar[m_][0], Br[(nh)*2+n_][0], acc[(mh)*4+m_][(nh)*2+n_], 0, 0, 0);          \
      acc[(mh)*4+m_][(nh)*2+n_] = __builtin_amdgcn_mfma_f32_16x16x32_bf16(           \
          Ar[m_][1], Br[(nh)*2+n_][1], acc[(mh)*4+m_][(nh)*2+n_], 0, 0, 0);          \
    } }                                                                              \
  __builtin_amdgcn_s_setprio(0);                                                     \
} while (0)

__global__ __launch_bounds__(512, 2)
void gemm8_k(const u16* __restrict__ Ab, const u16* __restrict__ Bb,
             const float* __restrict__ bias, float* __restrict__ out) {
  extern __shared__ u16 smem[];           // 2 bufs x (A 16384 + B 16384) elems = 128 KiB
  const int tid  = threadIdx.x;
  const int wave = tid >> 6;
  const int lane = tid & 63;
  const int lr = lane & 15, lg = lane >> 4;
  const int wm = wave >> 2, wn = wave & 3;

  // T1: bijective XCD swizzle (512 % 8 == 0)
  const int wg  = blockIdx.x;
  const int swz = (wg & 7) * 64 + (wg >> 3);
  const int m0 = (swz >> 4) * 256;
  const int n0 = (swz & 15) * 256;

  // ds_read addressing (T2 swizzle: 16B-block cb ^= row&7; row&7 == lr&7)
  const int aoff = wm * 8192 + lr * 64;
  const int boff = 16384 + wn * 4096 + lr * 64;
  const int e7   = lr & 7;
  const int blk0 = ((0 + lg) ^ e7) * 8;
  const int blk1 = ((4 + lg) ^ e7) * 8;

  // staging: thread t covers row tid>>3 (of 64-row issue), source col pre-swizzled
  const int srow = tid >> 3;
  const int scol = ((tid & 7) ^ (srow & 7)) * 8;
  const int woff = wave * 512;

  const u16* aRow = Ab + (size_t)(m0 + srow) * KCAT + scol;
  const u16* bRow = Bb + (size_t)(n0 + srow) * KCAT + scol;
  u16* dstA0 = smem + woff;            // buf0 A h=0 (h=1 at +8192; buf1 at +BUF1)
  u16* dstB0 = smem + 16384 + woff;

  bf16x8 Ar[4][2], Br[4][2];
  f32x4 acc[8][4] = {};

  // stage one half-tile (128 rows x 64 k): branchless, base + k-offset
  auto stgA = [&](int kof, int h, int bufel) {
    u16* dst = dstA0 + bufel + h * 8192;
    gld_lds16(aRow + (size_t)(h * 128) * KCAT + kof, dst);
    gld_lds16(aRow + (size_t)(h * 128 + 64) * KCAT + kof, dst + 4096);
  };
  auto stgB = [&](int kof, int h, int bufel) {
    u16* dst = dstB0 + bufel + h * 8192;
    gld_lds16(bRow + (size_t)(h * 128) * KCAT + kof, dst);
    gld_lds16(bRow + (size_t)(h * 128 + 64) * KCAT + kof, dst + 4096);
  };

  // prologue: tile0 full (buf0), then t1.B0,B1,A0 (buf1); gate tile0 (oldest 8 of 14)
  stgA(0, 0, 0);     stgA(0, 1, 0);
  stgB(0, 0, 0);     stgB(0, 1, 0);
  stgB(64, 0, BUF1); stgB(64, 1, BUF1);
  stgA(64, 0, BUF1);
  VMW6();
  BAR();

  for (int it = 0; it < NTILE / 2; ++it) {
    const int ka = it * 128;                       // tile a k-offset (elements)
    int c2 = ka + 128, c3 = ka + 192;              // prefetch tiles a+2, a+3
    if (c2 > (NTILE - 1) * 64) c2 = (NTILE - 1) * 64;   // tail: re-stage junk
    if (c3 > (NTILE - 1) * 64) c3 = (NTILE - 1) * 64;
    // P1: Q00(a) | stage b.A1 -> buf1
    LDA(0, 0); LDB(0, 0);
    stgA(ka + 64, 1, BUF1);
    BAR(); MMQ(0, 0); BAR();
    // P2: Q01(a)
    LDB(0, 1);
    BAR(); MMQ(0, 1); BAR();
    // P3: Q11(a) | stage (a+2).B0,B1 -> buf0 (buf0.B read-done after P2)
    LDA(0, 1);
    stgB(c2, 0, 0); stgB(c2, 1, 0);
    BAR(); MMQ(1, 1); BAR();
    // P4: Q10(a) | stage (a+2).A0 -> buf0; gate tile b complete
    stgA(c2, 0, 0);
    BAR(); MMQ(1, 0);
    VMW6();
    BAR();
    // P5: Q00(b) | stage (a+2).A1 -> buf0
    LDA(BUF1, 0); LDB(BUF1, 0);
    stgA(c2, 1, 0);
    BAR(); MMQ(0, 0); BAR();
    // P6: Q01(b)
    LDB(BUF1, 1);
    BAR(); MMQ(0, 1); BAR();
    // P7: Q11(b) | stage (a+3).B0,B1 -> buf1 (buf1.B read-done after P6)
    LDA(BUF1, 1);
    stgB(c3, 0, BUF1); stgB(c3, 1, BUF1);
    BAR(); MMQ(1, 1); BAR();
    // P8: Q10(b) | stage (a+3).A0 -> buf1; gate tile a+2 complete
    stgA(c3, 0, BUF1);
    BAR(); MMQ(1, 0);
    VMW6();
    BAR();
  }

  // epilogue: bias + store (C/D mapping: row=...+lg*4+j, col=...+lr)
  float bv[4];
  #pragma unroll
  for (int n = 0; n < 4; ++n) bv[n] = bias[n0 + wn * 64 + n * 16 + lr];
  #pragma unroll
  for (int m = 0; m < 8; ++m) {
    const int row = m0 + wm * 128 + m * 16 + lg * 4;
    #pragma unroll
    for (int n = 0; n < 4; ++n) {
      const int col = n0 + wn * 64 + n * 16 + lr;
      float* op = out + (size_t)row * N_TOT + col;
      op[0 * (size_t)N_TOT] = acc[m][n][0] + bv[n];
      op[1 * (size_t)N_TOT] = acc[m][n][1] + bv[n];
      op[2 * (size_t)N_TOT] = acc[m][n][2] + bv[n];
      op[3 * (size_t)N_TOT] = acc[m][n][3] + bv[n];
    }
  }
}

extern "C" void kernel_launch(void* const* d_in, const int* in_sizes, int n_in,
                              void* d_out, int out_size, void* d_ws, size_t ws_size,
                              hipStream_t stream) {
  const float* x    = (const float*)d_in[0];
  const float* ss   = (const float*)d_in[1];
  const float* wq   = (const float*)d_in[2];
  const float* la   = (const float*)d_in[3];
  const float* lb   = (const float*)d_in[4];
  const float* wsp  = (const float*)d_in[5];
  const float* bias = (const float*)d_in[6];
  float* out = (float*)d_out;

  uint8_t* w = (uint8_t*)d_ws;
  u16* Ab  = (u16*)w;  w += (size_t)M_TOT * KCAT * 2;    // 130.0 MiB
  u16* Bb  = (u16*)w;  w += (size_t)N_TOT * KCAT * 2;    // 65.0 MiB
  u16* asb = (u16*)w;                                     // 0.25 MiB

  prep_as_k<<<128, 256, 0, stream>>>(la, ss, asb);
  cvt_w_k<<<16384, 256, 0, stream>>>(wq,  Bb, 0);
  cvt_w_k<<<16384, 256, 0, stream>>>(wsp, Bb, K_DIN);
  cvt_lb_k<<<128, 256, 0, stream>>>(lb, Bb);
  prep_x_k<<<M_TOT, 256, 0, stream>>>(x, ss, Ab);
  lora_t_mfma_k<<<M_TOT / 64, 256, 0, stream>>>(Ab, asb);

  hipFuncSetAttribute((const void*)gemm8_k,
                      hipFuncAttributeMaxDynamicSharedMemorySize, 131072);
  gemm8_k<<<dim3((N_TOT / 256) * (M_TOT / 256)), 512, 131072, stream>>>(
      Ab, Bb, bias, out);
}